// Round 2
// baseline (658.465 us; speedup 1.0000x reference)
//
#include <hip/hip_runtime.h>
#include <hip/hip_bf16.h>

typedef unsigned short u16;
typedef __bf16 bf16x8 __attribute__((ext_vector_type(8)));
typedef float floatx4 __attribute__((ext_vector_type(4)));
typedef unsigned short u16x4 __attribute__((ext_vector_type(4)));
typedef unsigned short u16x8 __attribute__((ext_vector_type(8)));

__device__ __forceinline__ float b2f(u16 v) {
  unsigned u = ((unsigned)v) << 16;
  return __builtin_bit_cast(float, u);
}
__device__ __forceinline__ u16 f2b(float f) {
  unsigned u = __builtin_bit_cast(unsigned, f);
  unsigned r = (u + 0x7FFFu + ((u >> 16) & 1u)) >> 16;
  return (u16)r;
}
__device__ __forceinline__ void cp16(const u16* g, u16* l) {
  __builtin_amdgcn_global_load_lds(
      (const __attribute__((address_space(1))) unsigned int*)g,
      (__attribute__((address_space(3))) unsigned int*)l, 16, 0, 0);
}

struct GemmArgs {
  const u16* A;
  const u16* BT0; const u16* BT1; const u16* BT2;
  const float* b0; const float* b1; const float* b2;
  const float* summ;   // nullable
  int srow0;
  u16* C0; u16* C1; u16* C2;   // bf16 outputs (ignored when Cf != null)
  float* Cf;                   // f32 output
};

// ---------------------------------------------------------------------------
// Small-M GEMM (kept for the 128-row summary branch): 128x128 tiles.
// ---------------------------------------------------------------------------
__global__ __launch_bounds__(256, 2) void gemm_bt(GemmArgs g) {
  const int z = blockIdx.z;
  const u16* A      = g.A;
  const u16* BT     = (z == 0) ? g.BT0 : (z == 1 ? g.BT1 : g.BT2);
  const float* bias = (z == 0) ? g.b0  : (z == 1 ? g.b1  : g.b2);
  u16* C            = (z == 0) ? g.C0  : (z == 1 ? g.C1  : g.C2);

  __shared__ u16 As[128 * 32];
  __shared__ u16 Bs[128 * 32];

  const int tid  = threadIdx.x;
  const int lane = tid & 63;
  const int wave = tid >> 6;
  const int quad = lane >> 4;
  const int cl   = lane & 15;
  const int wm   = wave & 1;
  const int wn   = wave >> 1;

  const size_t row0 = (size_t)blockIdx.x * 128;
  const size_t col0 = (size_t)blockIdx.y * 128;

  const int srow = lane >> 2;
  const int soff = (lane & 3) << 3;

  const u16* gA0 = A + (row0 + (size_t)(wave * 16 + srow)) * 1024 + soff;
  const u16* gA1 = gA0 + (size_t)64 * 1024;
  const u16* gB0 = BT + (col0 + (size_t)(wave * 16 + srow)) * 1024 + soff;
  const u16* gB1 = gB0 + (size_t)64 * 1024;
  u16* lA0 = As + wave * 512 + lane * 8;
  u16* lA1 = lA0 + 2048;
  u16* lB0 = Bs + wave * 512 + lane * 8;
  u16* lB1 = lB0 + 2048;

  floatx4 acc[4][4] = {};

  for (int kt = 0; kt < 1024; kt += 32) {
    __syncthreads();
    cp16(gA0, lA0); cp16(gA1, lA1);
    cp16(gB0, lB0); cp16(gB1, lB1);
    gA0 += 32; gA1 += 32; gB0 += 32; gB1 += 32;
    __syncthreads();
    bf16x8 af[4], bfr[4];
#pragma unroll
    for (int m = 0; m < 4; ++m)
      af[m] = *(const bf16x8*)&As[(wm * 64 + m * 16 + cl) * 32 + quad * 8];
#pragma unroll
    for (int n = 0; n < 4; ++n)
      bfr[n] = *(const bf16x8*)&Bs[(wn * 64 + n * 16 + cl) * 32 + quad * 8];
#pragma unroll
    for (int m = 0; m < 4; ++m)
#pragma unroll
      for (int n = 0; n < 4; ++n)
        acc[m][n] = __builtin_amdgcn_mfma_f32_16x16x32_bf16(af[m], bfr[n],
                                                            acc[m][n], 0, 0, 0);
  }

  const float* summ = g.summ;
#pragma unroll
  for (int m = 0; m < 4; ++m) {
    const size_t rbase = row0 + wm * 64 + m * 16 + quad * 4;
#pragma unroll
    for (int n = 0; n < 4; ++n) {
      const size_t c = col0 + wn * 64 + n * 16 + cl;
      const float bb = bias[c];
#pragma unroll
      for (int e = 0; e < 4; ++e) {
        float v = acc[m][n][e] + bb;
        if (summ)
          v += summ[(size_t)((int)((rbase + e) >> 8) + g.srow0) * 1024 + c];
        if (g.Cf) g.Cf[(rbase + e) * 1024 + c] = v;
        else      C[(rbase + e) * 1024 + c] = f2b(v);
      }
    }
  }
}

// ---------------------------------------------------------------------------
// 256x256-tile GEMM, register-pipelined 4-phase schedule.
//  - fragment reuse order (0,0)->(0,1)->(1,1)->(1,0): 24 ds_read_b128/tile/wave
//  - each phase issues NEXT phase's ds_reads (disjoint reg sets) + 1 stage
//    unit + 16 MFMA; lgkmcnt(0); ONE barrier.
//  - tile u stages all 4 units of tile u+2; uniform s_waitcnt vmcnt(8) at the
//    top of every phase retires exactly the 5-phase-old stage (1 barrier
//    before its readers). Tail tiles 14/15 drain 8/6/4/2/0.
//  - T2 swizzle: phys colbyte = logical ^ ((row&7)<<4); linear LDS dest +
//    inverse-swizzled global source + swizzled ds_read (unchanged, verified).
// ---------------------------------------------------------------------------
__global__ __launch_bounds__(512, 2) void gemm_bt256(GemmArgs g) {
  extern __shared__ char lds[];
  const int z = blockIdx.z;
  const u16* A      = g.A;
  const u16* BT     = (z == 0) ? g.BT0 : (z == 1 ? g.BT1 : g.BT2);
  const float* bias = (z == 0) ? g.b0  : (z == 1 ? g.b1  : g.b2);
  u16* C            = (z == 0) ? g.C0  : (z == 1 ? g.C1  : g.C2);

  const int tid  = threadIdx.x;
  const int lane = tid & 63;
  const int w    = tid >> 6;   // 0..7
  const int q    = lane >> 4;
  const int cl   = lane & 15;
  const int wm   = w >> 2;     // 0..1
  const int wn   = w & 3;      // 0..3

  const size_t row0 = (size_t)blockIdx.x * 256;
  const size_t col0 = (size_t)blockIdx.y * 256;

  // staging source (per-lane inverse-swizzled global address)
  const int lr  = lane >> 3;
  const int lcs = ((lane & 7) ^ lr) * 8;
  const u16* Ab = A  + (row0 + (size_t)lr) * 1024 + lcs;
  const u16* Bb = BT + (col0 + (size_t)lr) * 1024 + lcs;
  const int wa8 = w * 8;
  const int wbr = (w >> 2) * 64 + (w & 3) * 8;

  // swizzled ds_read bases
  const int swz = (cl & 7) << 4;
  const int aB0 = (wm * 128 + cl) * 128 + ((q * 16) ^ swz);
  const int aB1 = aB0 ^ 64;
  const int bB0 = 32768 + (wn * 64 + cl) * 128 + ((q * 16) ^ swz);
  const int bB1 = bB0 ^ 64;

  char* const L0 = lds;
  char* const L1 = lds + 65536;

  floatx4 acc[8][4] = {};
  bf16x8 aQ0_0[4], aQ0_1[4], aQ1_0[4], aQ1_1[4];
  bf16x8 bS0_0[2], bS0_1[2], bS1_0[2], bS1_1[2];

#define VMW(N) asm volatile("s_waitcnt vmcnt(" #N ")" ::: "memory");
#define LGK0   asm volatile("s_waitcnt lgkmcnt(0)" ::: "memory");
#define BAR    __builtin_amdgcn_s_barrier();

#define STAGE_A(QA, T, LBASE)                                                 \
  { const int r0s = (QA) * 64 + wa8;                                          \
    cp16(Ab + (size_t)r0s * 1024 + (size_t)(T) * 64,                          \
         (u16*)((LBASE) + r0s * 128));                                        \
    const int r1s = r0s + 128;                                                \
    cp16(Ab + (size_t)r1s * 1024 + (size_t)(T) * 64,                          \
         (u16*)((LBASE) + r1s * 128)); }

#define STAGE_B(QB, T, LBASE)                                                 \
  { const int r0s = wbr + (QB) * 32;                                          \
    cp16(Bb + (size_t)r0s * 1024 + (size_t)(T) * 64,                          \
         (u16*)((LBASE) + 32768 + r0s * 128));                                \
    const int r1s = r0s + 128;                                                \
    cp16(Bb + (size_t)r1s * 1024 + (size_t)(T) * 64,                          \
         (u16*)((LBASE) + 32768 + r1s * 128)); }

#define RD_A(D0, D1, QM, LB)                                                  \
  _Pragma("unroll") for (int mm = 0; mm < 4; ++mm) {                          \
    const int ro = (QM) * 8192 + mm * 2048;                                   \
    D0[mm] = *(const bf16x8*)((LB) + aB0 + ro);                               \
    D1[mm] = *(const bf16x8*)((LB) + aB1 + ro);                               \
  }

#define RD_B(D0, D1, QN, LB)                                                  \
  _Pragma("unroll") for (int nn = 0; nn < 2; ++nn) {                          \
    const int co = (QN) * 4096 + nn * 2048;                                   \
    D0[nn] = *(const bf16x8*)((LB) + bB0 + co);                               \
    D1[nn] = *(const bf16x8*)((LB) + bB1 + co);                               \
  }

#define MM(QM, QN, A0, A1, B0, B1)                                            \
  __builtin_amdgcn_s_setprio(1);                                              \
  _Pragma("unroll") for (int mm = 0; mm < 4; ++mm)                            \
    _Pragma("unroll") for (int nn = 0; nn < 2; ++nn)                          \
      acc[(QM) * 4 + mm][(QN) * 2 + nn] =                                     \
          __builtin_amdgcn_mfma_f32_16x16x32_bf16(                            \
              A0[mm], B0[nn], acc[(QM) * 4 + mm][(QN) * 2 + nn], 0, 0, 0);    \
  _Pragma("unroll") for (int mm = 0; mm < 4; ++mm)                            \
    _Pragma("unroll") for (int nn = 0; nn < 2; ++nn)                          \
      acc[(QM) * 4 + mm][(QN) * 2 + nn] =                                     \
          __builtin_amdgcn_mfma_f32_16x16x32_bf16(                            \
              A1[mm], B1[nn], acc[(QM) * 4 + mm][(QN) * 2 + nn], 0, 0, 0);    \
  __builtin_amdgcn_s_setprio(0);

  // ---- prologue: stage tiles 0 and 1 (order = steady-state issue order) ----
  STAGE_A(0, 0, L0) STAGE_B(0, 0, L0) STAGE_B(1, 0, L0) STAGE_A(1, 0, L0)
  STAGE_A(0, 1, L1) STAGE_B(0, 1, L1) STAGE_B(1, 1, L1) STAGE_A(1, 1, L1)
  VMW(8)   // tile 0 retired; tile 1's 8 loads in flight
  BAR      // cross-wave: all waves' tile-0 loads retired
  RD_A(aQ0_0, aQ0_1, 0, L0)
  RD_B(bS0_0, bS0_1, 0, L0)
  LGK0 BAR

  // ---- main loop: tiles 0..13, tile u stages tile u+2 ----
#pragma unroll 1
  for (int u0 = 0; u0 < 14; u0 += 2) {
    // tile u0 (buf L0), stage -> L0
    VMW(8) STAGE_A(0, u0 + 2, L0)
    RD_B(bS1_0, bS1_1, 1, L0)
    MM(0, 0, aQ0_0, aQ0_1, bS0_0, bS0_1)
    LGK0 BAR
    VMW(8) STAGE_B(0, u0 + 2, L0)
    RD_A(aQ1_0, aQ1_1, 1, L0)
    MM(0, 1, aQ0_0, aQ0_1, bS1_0, bS1_1)
    LGK0 BAR
    VMW(8) STAGE_B(1, u0 + 2, L0)
    RD_A(aQ0_0, aQ0_1, 0, L1)
    MM(1, 1, aQ1_0, aQ1_1, bS1_0, bS1_1)
    LGK0 BAR
    VMW(8) STAGE_A(1, u0 + 2, L0)
    MM(1, 0, aQ1_0, aQ1_1, bS0_0, bS0_1)   // consumes old bS0 ...
    RD_B(bS0_0, bS0_1, 0, L1)              // ... then overwrite (WAR ordered)
    LGK0 BAR
    // tile u0+1 (buf L1), stage -> L1
    VMW(8) STAGE_A(0, u0 + 3, L1)
    RD_B(bS1_0, bS1_1, 1, L1)
    MM(0, 0, aQ0_0, aQ0_1, bS0_0, bS0_1)
    LGK0 BAR
    VMW(8) STAGE_B(0, u0 + 3, L1)
    RD_A(aQ1_0, aQ1_1, 1, L1)
    MM(0, 1, aQ0_0, aQ0_1, bS1_0, bS1_1)
    LGK0 BAR
    VMW(8) STAGE_B(1, u0 + 3, L1)
    RD_A(aQ0_0, aQ0_1, 0, L0)
    MM(1, 1, aQ1_0, aQ1_1, bS1_0, bS1_1)
    LGK0 BAR
    VMW(8) STAGE_A(1, u0 + 3, L1)
    MM(1, 0, aQ1_0, aQ1_1, bS0_0, bS0_1)
    RD_B(bS0_0, bS0_1, 0, L0)
    LGK0 BAR
  }

  // ---- tail: tile 14 (L0, no stage, draining vmcnt), tile 15 (L1) ----
  VMW(8)
  RD_B(bS1_0, bS1_1, 1, L0)
  MM(0, 0, aQ0_0, aQ0_1, bS0_0, bS0_1)
  LGK0 BAR
  VMW(6)
  RD_A(aQ1_0, aQ1_1, 1, L0)
  MM(0, 1, aQ0_0, aQ0_1, bS1_0, bS1_1)
  LGK0 BAR
  VMW(4)
  RD_A(aQ0_0, aQ0_1, 0, L1)
  MM(1, 1, aQ1_0, aQ1_1, bS1_0, bS1_1)
  LGK0 BAR
  VMW(2)
  MM(1, 0, aQ1_0, aQ1_1, bS0_0, bS0_1)
  RD_B(bS0_0, bS0_1, 0, L1)
  LGK0 BAR
  VMW(0)
  RD_B(bS1_0, bS1_1, 1, L1)
  MM(0, 0, aQ0_0, aQ0_1, bS0_0, bS0_1)
  LGK0 BAR
  RD_A(aQ1_0, aQ1_1, 1, L1)
  MM(0, 1, aQ0_0, aQ0_1, bS1_0, bS1_1)
  MM(1, 1, aQ1_0, aQ1_1, bS1_0, bS1_1)
  MM(1, 0, aQ1_0, aQ1_1, bS0_0, bS0_1)

#undef MM
#undef RD_B
#undef RD_A
#undef STAGE_B
#undef STAGE_A
#undef BAR
#undef LGK0
#undef VMW

  const float* summ = g.summ;
#pragma unroll
  for (int m = 0; m < 8; ++m) {
    const size_t rbase = row0 + wm * 128 + m * 16 + q * 4;
#pragma unroll
    for (int n = 0; n < 4; ++n) {
      const size_t c = col0 + wn * 64 + n * 16 + cl;
      const float bb = bias[c];
#pragma unroll
      for (int e = 0; e < 4; ++e) {
        float v = acc[m][n][e] + bb;
        if (summ)
          v += summ[(size_t)((int)((rbase + e) >> 8) + g.srow0) * 1024 + c];
        if (g.Cf) g.Cf[(rbase + e) * 1024 + c] = v;
        else      C[(rbase + e) * 1024 + c] = f2b(v);
      }
    }
  }
}

// ---------------------------------------------------------------------------
// Local block attention. grid (4 qtiles, 16 heads, nblk), 256 threads.
// ---------------------------------------------------------------------------
__global__ __launch_bounds__(256, 2) void local_attn(
    const u16* __restrict__ Q, const u16* __restrict__ Kt,
    const u16* __restrict__ Vt, const float* __restrict__ pbias,
    u16* __restrict__ ctx) {
  const int qt  = blockIdx.x;
  const int h   = blockIdx.y;
  const int blk = blockIdx.z;
  const int tid  = threadIdx.x;
  const int lane = tid & 63;
  const int w    = tid >> 6;
  const int quad = lane >> 4;
  const int cl   = lane & 15;

  __shared__ u16 BufA[64 * 72];
  __shared__ u16 BufB[64 * 72];

  const size_t tok0  = (size_t)blk * 256;
  const size_t qrow0 = tok0 + qt * 64;
  const int hc = h * 64;

  for (int i = tid; i < 512; i += 256) {
    const int row = i >> 3, c8 = (i & 7) * 8;
    *(u16x8*)&BufA[row * 72 + c8] =
        *(const u16x8*)&Q[(qrow0 + row) * 1024 + hc + c8];
  }

  floatx4 accS[16] = {};
#pragma unroll
  for (int kc = 0; kc < 4; ++kc) {
    __syncthreads();
    for (int i = tid; i < 512; i += 256) {
      const int row = i >> 3, c8 = (i & 7) * 8;
      *(u16x8*)&BufB[row * 72 + c8] =
          *(const u16x8*)&Kt[(tok0 + kc * 64 + row) * 1024 + hc + c8];
    }
    __syncthreads();
#pragma unroll
    for (int ki = 0; ki < 2; ++ki) {
      const bf16x8 aq =
          *(const bf16x8*)&BufA[(w * 16 + cl) * 72 + ki * 32 + quad * 8];
#pragma unroll
      for (int n = 0; n < 4; ++n) {
        const bf16x8 bk =
            *(const bf16x8*)&BufB[(n * 16 + cl) * 72 + ki * 32 + quad * 8];
        accS[kc * 4 + n] = __builtin_amdgcn_mfma_f32_16x16x32_bf16(
            aq, bk, accS[kc * 4 + n], 0, 0, 0);
      }
    }
  }

  float mrow[4] = {-1e30f, -1e30f, -1e30f, -1e30f};
#pragma unroll
  for (int r = 0; r < 4; ++r) {
    const float* brow = pbias + ((size_t)h << 16) +
                        (size_t)(qt * 64 + w * 16 + quad * 4 + r) * 256 + cl;
#pragma unroll
    for (int n = 0; n < 16; ++n) {
      float s = accS[n][r] * 0.125f + brow[n * 16];
      accS[n][r] = s;
      mrow[r] = fmaxf(mrow[r], s);
    }
  }
#pragma unroll
  for (int r = 0; r < 4; ++r) {
#pragma unroll
    for (int st = 1; st < 16; st <<= 1)
      mrow[r] = fmaxf(mrow[r], __shfl_xor(mrow[r], st));
  }
  float lsum[4] = {0.f, 0.f, 0.f, 0.f};
#pragma unroll
  for (int n = 0; n < 16; ++n) {
#pragma unroll
    for (int r = 0; r < 4; ++r) {
      float p = exp2f((accS[n][r] - mrow[r]) * 1.44269504f);
      accS[n][r] = p;
      lsum[r] += p;
    }
  }
#pragma unroll
  for (int r = 0; r < 4; ++r) {
#pragma unroll
    for (int st = 1; st < 16; st <<= 1)
      lsum[r] += __shfl_xor(lsum[r], st);
  }

  floatx4 accO[4] = {};
#pragma unroll
  for (int kc = 0; kc < 4; ++kc) {
    __syncthreads();
#pragma unroll
    for (int nn = 0; nn < 4; ++nn)
#pragma unroll
      for (int r = 0; r < 4; ++r)
        BufA[(w * 16 + quad * 4 + r) * 72 + nn * 16 + cl] =
            f2b(accS[kc * 4 + nn][r]);
    for (int i = tid; i < 512; i += 256) {
      const int key = i & 63, dh0 = (i >> 6) * 8;
      u16x8 v = *(const u16x8*)&Vt[(tok0 + kc * 64 + key) * 1024 + hc + dh0];
#pragma unroll
      for (int j = 0; j < 8; ++j) BufB[(dh0 + j) * 72 + key] = v[j];
    }
    __syncthreads();
#pragma unroll
    for (int ki = 0; ki < 2; ++ki) {
      const bf16x8 ap =
          *(const bf16x8*)&BufA[(w * 16 + cl) * 72 + ki * 32 + quad * 8];
#pragma unroll
      for (int nd = 0; nd < 4; ++nd) {
        const bf16x8 bv =
            *(const bf16x8*)&BufB[(nd * 16 + cl) * 72 + ki * 32 + quad * 8];
        accO[nd] = __builtin_amdgcn_mfma_f32_16x16x32_bf16(ap, bv, accO[nd],
                                                           0, 0, 0);
      }
    }
  }

  float inv[4];
#pragma unroll
  for (int r = 0; r < 4; ++r) inv[r] = 1.0f / lsum[r];
#pragma unroll
  for (int nd = 0; nd < 4; ++nd)
#pragma unroll
    for (int r = 0; r < 4; ++r)
      ctx[(qrow0 + w * 16 + quad * 4 + r) * 1024 + hc + nd * 16 + cl] =
          f2b(accO[nd][r] * inv[r]);
}

// ---------------------------------------------------------------------------
// Conversions & summary-branch helpers
// ---------------------------------------------------------------------------
__global__ void cvt_x(const float* __restrict__ x, u16* __restrict__ xb) {
  const size_t i = ((size_t)blockIdx.x * 256 + threadIdx.x) * 4;
  float4 v = *(const float4*)&x[i];
  u16x4 o;
  o[0] = f2b(v.x); o[1] = f2b(v.y); o[2] = f2b(v.z); o[3] = f2b(v.w);
  *(u16x4*)&xb[i] = o;
}

__global__ void block_mean(const float* __restrict__ x, u16* __restrict__ xm) {
  const int g = blockIdx.x >> 2;
  const int d = ((blockIdx.x & 3) << 8) + threadIdx.x;
  const float* p = x + (size_t)g * 256 * 1024 + d;
  float s = 0.f;
  for (int t = 0; t < 256; ++t) s += p[(size_t)t * 1024];
  xm[(size_t)g * 1024 + d] = f2b(s * (1.0f / 256.0f));
}

__global__ void summ_attn(const u16* __restrict__ SQ, const u16* __restrict__ SK,
                          const u16* __restrict__ SV, u16* __restrict__ sctx) {
  const int b = blockIdx.x >> 4;
  const int h = blockIdx.x & 15;
  const int t = threadIdx.x;
  __shared__ float Qf[16][64];
  __shared__ float Kf[16][64];
  __shared__ float Vf[16][64];
  __shared__ float sc[16][16];
  for (int i = t; i < 1024; i += 64) {
    const int r = i >> 6, d = i & 63;
    const size_t off = (size_t)(b * 16 + r) * 1024 + h * 64 + d;
    Qf[r][d] = b2f(SQ[off]);
    Kf[r][d] = b2f(SK[off]);
    Vf[r][d] = b2f(SV[off]);
  }
  __syncthreads();
  {
    const int i = t >> 2, j0 = t & 3;
#pragma unroll
    for (int jj = 0; jj < 4; ++jj) {
      const int j = j0 + jj * 4;
      float s = 0.f;
      for (int d = 0; d < 64; ++d) s += Qf[i][d] * Kf[j][d];
      sc[i][j] = s * 0.125f;
    }
  }
  __syncthreads();
  if (t < 16) {
    float m = -1e30f;
    for (int j = 0; j < 16; ++j) m = fmaxf(m, sc[t][j]);
    float l = 0.f;
    for (int j = 0; j < 16; ++j) {
      float p = exp2f((sc[t][j] - m) * 1.44269504f);
      sc[t][j] = p;
      l += p;
    }
    const float inv = 1.0f / l;
    for (int j = 0; j < 16; ++j) sc[t][j] *= inv;
  }
  __syncthreads();
  {
    const int i = t >> 2, d0 = (t & 3) * 16;
    for (int dd = 0; dd < 16; ++dd) {
      float a = 0.f;
      for (int j = 0; j < 16; ++j) a += sc[i][j] * Vf[j][d0 + dd];
      sctx[(size_t)(b * 16 + i) * 1024 + h * 64 + d0 + dd] = f2b(a);
    }
  }
}

struct TPtrs { const float* src[9]; u16* dst[9]; };

__global__ void cvt_transpose9(TPtrs p) {
  const float* src = p.src[blockIdx.z];
  u16* dst         = p.dst[blockIdx.z];
  __shared__ u16 tile[64][72];
  const int r0 = blockIdx.x * 64, c0 = blockIdx.y * 64;
  for (int i = threadIdx.x; i < 1024; i += 256) {
    const int row = i >> 4, c4 = (i & 15) * 4;
    float4 v = *(const float4*)&src[(size_t)(r0 + row) * 1024 + c0 + c4];
    tile[row][c4 + 0] = f2b(v.x);
    tile[row][c4 + 1] = f2b(v.y);
    tile[row][c4 + 2] = f2b(v.z);
    tile[row][c4 + 3] = f2b(v.w);
  }
  __syncthreads();
  for (int i = threadIdx.x; i < 512; i += 256) {
    const int row = i >> 3, c8 = (i & 7) * 8;
    u16x8 v;
#pragma unroll
    for (int j = 0; j < 8; ++j) v[j] = tile[c8 + j][row];
    *(u16x8*)&dst[(size_t)(c0 + row) * 1024 + r0 + c8] = v;
  }
}

// ---------------------------------------------------------------------------
extern "C" void kernel_launch(void* const* d_in, const int* in_sizes, int n_in,
                              void* d_out, int out_size, void* d_ws, size_t ws_size,
                              hipStream_t stream) {
  const float* x    = (const float*)d_in[0];
  const float* lqw  = (const float*)d_in[1];
  const float* lqb  = (const float*)d_in[2];
  const float* lkw  = (const float*)d_in[3];
  const float* lkb  = (const float*)d_in[4];
  const float* lvw  = (const float*)d_in[5];
  const float* lvb  = (const float*)d_in[6];
  const float* low_ = (const float*)d_in[7];
  const float* lob  = (const float*)d_in[8];
  const float* pb   = (const float*)d_in[9];
  const float* sqw  = (const float*)d_in[10];
  const float* sqb  = (const float*)d_in[11];
  const float* skw  = (const float*)d_in[12];
  const float* skb  = (const float*)d_in[13];
  const float* svw  = (const float*)d_in[14];
  const float* svb  = (const float*)d_in[15];
  const float* sow  = (const float*)d_in[16];
  const float* sob  = (const float*)d_in[17];
  const float* smw  = (const float*)d_in[18];
  const float* smb  = (const float*)d_in[19];

  static int s_attr_done = 0;
  if (!s_attr_done) {
    (void)hipFuncSetAttribute((const void*)gemm_bt256,
                              hipFuncAttributeMaxDynamicSharedMemorySize,
                              131072);
    s_attr_done = 1;
  }

  char* W = (char*)d_ws;
  size_t off = 0;
  u16* wt[9];
  for (int i = 0; i < 9; ++i) { wt[i] = (u16*)(W + off); off += (size_t)1024 * 1024 * 2; }
  u16* Xb  = (u16*)(W + off); off += (size_t)16384 * 1024 * 2;
  u16* XM  = (u16*)(W + off); off += (size_t)128 * 1024 * 2;
  u16* SMR = (u16*)(W + off); off += (size_t)128 * 1024 * 2;
  u16* SQp = (u16*)(W + off); off += (size_t)128 * 1024 * 2;
  u16* SKp = (u16*)(W + off); off += (size_t)128 * 1024 * 2;
  u16* SVp = (u16*)(W + off); off += (size_t)128 * 1024 * 2;
  u16* SCT = (u16*)(W + off); off += (size_t)128 * 1024 * 2;
  float* SMM = (float*)(W + off); off += (size_t)128 * 1024 * 4;
  const size_t fixedB = off;

  int CH = 256;
  for (int c = 16384; c >= 256; c >>= 1) {
    if (fixedB + (size_t)4 * c * 1024 * 2 <= ws_size) { CH = c; break; }
  }
  u16* Qb  = (u16*)(W + fixedB);
  u16* Kb  = Qb + (size_t)CH * 1024;
  u16* Vb  = Kb + (size_t)CH * 1024;
  u16* CTX = Vb + (size_t)CH * 1024;

  TPtrs tp;
  tp.src[0] = lqw; tp.src[1] = lkw; tp.src[2] = lvw; tp.src[3] = low_;
  tp.src[4] = sqw; tp.src[5] = skw; tp.src[6] = svw; tp.src[7] = sow;
  tp.src[8] = smw;
  for (int i = 0; i < 9; ++i) tp.dst[i] = wt[i];
  cvt_transpose9<<<dim3(16, 16, 9), 256, 0, stream>>>(tp);

  cvt_x<<<dim3(16384), 256, 0, stream>>>(x, Xb);
  block_mean<<<dim3(256), 256, 0, stream>>>(x, XM);

  GemmArgs g1{};
  g1.A = XM; g1.BT0 = g1.BT1 = g1.BT2 = wt[8];
  g1.b0 = g1.b1 = g1.b2 = smb; g1.summ = nullptr; g1.srow0 = 0;
  g1.C0 = g1.C1 = g1.C2 = SMR; g1.Cf = nullptr;
  gemm_bt<<<dim3(1, 8, 1), 256, 0, stream>>>(g1);

  GemmArgs g2{};
  g2.A = SMR; g2.BT0 = wt[4]; g2.BT1 = wt[5]; g2.BT2 = wt[6];
  g2.b0 = sqb; g2.b1 = skb; g2.b2 = svb; g2.summ = nullptr; g2.srow0 = 0;
  g2.C0 = SQp; g2.C1 = SKp; g2.C2 = SVp; g2.Cf = nullptr;
  gemm_bt<<<dim3(1, 8, 3), 256, 0, stream>>>(g2);

  summ_attn<<<dim3(64), 64, 0, stream>>>(SQp, SKp, SVp, SCT);

  GemmArgs g3{};
  g3.A = SCT; g3.BT0 = g3.BT1 = g3.BT2 = wt[7];
  g3.b0 = g3.b1 = g3.b2 = sob; g3.summ = nullptr; g3.srow0 = 0;
  g3.C0 = g3.C1 = g3.C2 = nullptr; g3.Cf = SMM;
  gemm_bt<<<dim3(1, 8, 1), 256, 0, stream>>>(g3);

  for (int base = 0; base < 16384; base += CH) {
    GemmArgs g4{};
    g4.A = Xb + (size_t)base * 1024;
    g4.BT0 = wt[0]; g4.BT1 = wt[1]; g4.BT2 = wt[2];
    g4.b0 = lqb; g4.b1 = lkb; g4.b2 = lvb; g4.summ = nullptr; g4.srow0 = 0;
    g4.C0 = Qb; g4.C1 = Kb; g4.C2 = Vb; g4.Cf = nullptr;
    gemm_bt256<<<dim3(CH / 256, 4, 3), 512, 131072, stream>>>(g4);

    local_attn<<<dim3(4, 16, CH / 256), 256, 0, stream>>>(Qb, Kb, Vb, pb, CTX);

    GemmArgs g5{};
    g5.A = CTX; g5.BT0 = g5.BT1 = g5.BT2 = wt[3];
    g5.b0 = g5.b1 = g5.b2 = lob; g5.summ = SMM; g5.srow0 = base >> 8;
    g5.C0 = g5.C1 = g5.C2 = nullptr;
    g5.Cf = (float*)d_out + (size_t)base * 1024;
    gemm_bt256<<<dim3(CH / 256, 4, 1), 512, 131072, stream>>>(g5);
  }

  (void)in_sizes; (void)n_in; (void)out_size;
}

// Round 3
// 510.599 us; speedup vs baseline: 1.2896x; 1.2896x over previous
//
#include <hip/hip_runtime.h>
#include <hip/hip_bf16.h>

typedef unsigned short u16;
typedef __bf16 bf16x8 __attribute__((ext_vector_type(8)));
typedef float floatx4 __attribute__((ext_vector_type(4)));
typedef unsigned short u16x4 __attribute__((ext_vector_type(4)));
typedef unsigned short u16x8 __attribute__((ext_vector_type(8)));

__device__ __forceinline__ float b2f(u16 v) {
  unsigned u = ((unsigned)v) << 16;
  return __builtin_bit_cast(float, u);
}
__device__ __forceinline__ u16 f2b(float f) {
  unsigned u = __builtin_bit_cast(unsigned, f);
  unsigned r = (u + 0x7FFFu + ((u >> 16) & 1u)) >> 16;
  return (u16)r;
}
__device__ __forceinline__ void cp16(const u16* g, u16* l) {
  __builtin_amdgcn_global_load_lds(
      (const __attribute__((address_space(1))) unsigned int*)g,
      (__attribute__((address_space(3))) unsigned int*)l, 16, 0, 0);
}

struct GemmArgs {
  const u16* A;
  const u16* BT0; const u16* BT1; const u16* BT2;
  const float* b0; const float* b1; const float* b2;
  const float* summ;   // nullable
  int srow0;
  u16* C0; u16* C1; u16* C2;   // bf16 outputs (ignored when Cf != null)
  float* Cf;                   // f32 output
};

// ---------------------------------------------------------------------------
// Small-M GEMM (kept for the 128-row summary branch): 128x128 tiles.
// ---------------------------------------------------------------------------
__global__ __launch_bounds__(256, 2) void gemm_bt(GemmArgs g) {
  const int z = blockIdx.z;
  const u16* A      = g.A;
  const u16* BT     = (z == 0) ? g.BT0 : (z == 1 ? g.BT1 : g.BT2);
  const float* bias = (z == 0) ? g.b0  : (z == 1 ? g.b1  : g.b2);
  u16* C            = (z == 0) ? g.C0  : (z == 1 ? g.C1  : g.C2);

  __shared__ u16 As[128 * 32];
  __shared__ u16 Bs[128 * 32];

  const int tid  = threadIdx.x;
  const int lane = tid & 63;
  const int wave = tid >> 6;
  const int quad = lane >> 4;
  const int cl   = lane & 15;
  const int wm   = wave & 1;
  const int wn   = wave >> 1;

  const size_t row0 = (size_t)blockIdx.x * 128;
  const size_t col0 = (size_t)blockIdx.y * 128;

  const int srow = lane >> 2;
  const int soff = (lane & 3) << 3;

  const u16* gA0 = A + (row0 + (size_t)(wave * 16 + srow)) * 1024 + soff;
  const u16* gA1 = gA0 + (size_t)64 * 1024;
  const u16* gB0 = BT + (col0 + (size_t)(wave * 16 + srow)) * 1024 + soff;
  const u16* gB1 = gB0 + (size_t)64 * 1024;
  u16* lA0 = As + wave * 512 + lane * 8;
  u16* lA1 = lA0 + 2048;
  u16* lB0 = Bs + wave * 512 + lane * 8;
  u16* lB1 = lB0 + 2048;

  floatx4 acc[4][4] = {};

  for (int kt = 0; kt < 1024; kt += 32) {
    __syncthreads();
    cp16(gA0, lA0); cp16(gA1, lA1);
    cp16(gB0, lB0); cp16(gB1, lB1);
    gA0 += 32; gA1 += 32; gB0 += 32; gB1 += 32;
    __syncthreads();
    bf16x8 af[4], bfr[4];
#pragma unroll
    for (int m = 0; m < 4; ++m)
      af[m] = *(const bf16x8*)&As[(wm * 64 + m * 16 + cl) * 32 + quad * 8];
#pragma unroll
    for (int n = 0; n < 4; ++n)
      bfr[n] = *(const bf16x8*)&Bs[(wn * 64 + n * 16 + cl) * 32 + quad * 8];
#pragma unroll
    for (int m = 0; m < 4; ++m)
#pragma unroll
      for (int n = 0; n < 4; ++n)
        acc[m][n] = __builtin_amdgcn_mfma_f32_16x16x32_bf16(af[m], bfr[n],
                                                            acc[m][n], 0, 0, 0);
  }

  const float* summ = g.summ;
#pragma unroll
  for (int m = 0; m < 4; ++m) {
    const size_t rbase = row0 + wm * 64 + m * 16 + quad * 4;
#pragma unroll
    for (int n = 0; n < 4; ++n) {
      const size_t c = col0 + wn * 64 + n * 16 + cl;
      const float bb = bias[c];
#pragma unroll
      for (int e = 0; e < 4; ++e) {
        float v = acc[m][n][e] + bb;
        if (summ)
          v += summ[(size_t)((int)((rbase + e) >> 8) + g.srow0) * 1024 + c];
        if (g.Cf) g.Cf[(rbase + e) * 1024 + c] = v;
        else      C[(rbase + e) * 1024 + c] = f2b(v);
      }
    }
  }
}

// ---------------------------------------------------------------------------
// 256x256-tile GEMM, m201-style 4-phase schedule, minimal register footprint.
//  - phases per tile: (0,0)->(0,1)->(1,1)->(1,0); held frags = ONE A-quadrant
//    (8 x bf16x8) + both B-halves (8 x bf16x8) = 64 VGPR (no spill; round-2's
//    96-VGPR live set spilled to scratch: WRITE_SIZE +89MB).
//  - reads per phase: 12/4/8/0 (24/tile = minimum); reads are for THIS phase:
//    {reads; stage; barrier; lgkmcnt(0); setprio(1); 16 MFMA; setprio(0); bar}
//  - staging 2-deep: tile u stages tile u+2 into the SAME buffer, each unit
//    one phase after its region's last reader. ONE s_waitcnt vmcnt(8) per
//    tile at P4-end BEFORE the barrier (cross-wave safe: every wave waits,
//    then barrier => all waves' tile-u+1 loads retired before P1 reads).
//  - T2 swizzle unchanged (verified: bank conflicts = 0).
// ---------------------------------------------------------------------------
__global__ __launch_bounds__(512, 2) void gemm_bt256(GemmArgs g) {
  extern __shared__ char lds[];
  const int z = blockIdx.z;
  const u16* A      = g.A;
  const u16* BT     = (z == 0) ? g.BT0 : (z == 1 ? g.BT1 : g.BT2);
  const float* bias = (z == 0) ? g.b0  : (z == 1 ? g.b1  : g.b2);
  u16* C            = (z == 0) ? g.C0  : (z == 1 ? g.C1  : g.C2);

  const int tid  = threadIdx.x;
  const int lane = tid & 63;
  const int w    = tid >> 6;   // 0..7
  const int q    = lane >> 4;
  const int cl   = lane & 15;
  const int wm   = w >> 2;     // 0..1
  const int wn   = w & 3;      // 0..3

  const size_t row0 = (size_t)blockIdx.x * 256;
  const size_t col0 = (size_t)blockIdx.y * 256;

  // staging source (per-lane inverse-swizzled global address)
  const int lr  = lane >> 3;
  const int lcs = ((lane & 7) ^ lr) * 8;
  const u16* Ab = A  + (row0 + (size_t)lr) * 1024 + lcs;
  const u16* Bb = BT + (col0 + (size_t)lr) * 1024 + lcs;
  const int wa8 = w * 8;
  const int wbr = (w >> 2) * 64 + (w & 3) * 8;

  // swizzled ds_read bases
  const int swz = (cl & 7) << 4;
  const int aB0 = (wm * 128 + cl) * 128 + ((q * 16) ^ swz);
  const int aB1 = aB0 ^ 64;
  const int bB0 = 32768 + (wn * 64 + cl) * 128 + ((q * 16) ^ swz);
  const int bB1 = bB0 ^ 64;

  char* const L0 = lds;
  char* const L1 = lds + 65536;

  floatx4 acc[8][4] = {};
  bf16x8 aF0[4], aF1[4];            // current A quadrant (k-half 0 / 1)
  bf16x8 b0h0[2], b0h1[2];          // B half s0
  bf16x8 b1h0[2], b1h1[2];          // B half s1

#define VMW(N) asm volatile("s_waitcnt vmcnt(" #N ")" ::: "memory");
#define LGK0   asm volatile("s_waitcnt lgkmcnt(0)" ::: "memory");
#define BAR    __builtin_amdgcn_s_barrier();

#define STAGE_A(QA, T, LBASE)                                                 \
  { const int r0s = (QA) * 64 + wa8;                                          \
    cp16(Ab + (size_t)r0s * 1024 + (size_t)(T) * 64,                          \
         (u16*)((LBASE) + r0s * 128));                                        \
    const int r1s = r0s + 128;                                                \
    cp16(Ab + (size_t)r1s * 1024 + (size_t)(T) * 64,                          \
         (u16*)((LBASE) + r1s * 128)); }

#define STAGE_B(QB, T, LBASE)                                                 \
  { const int r0s = wbr + (QB) * 32;                                          \
    cp16(Bb + (size_t)r0s * 1024 + (size_t)(T) * 64,                          \
         (u16*)((LBASE) + 32768 + r0s * 128));                                \
    const int r1s = r0s + 128;                                                \
    cp16(Bb + (size_t)r1s * 1024 + (size_t)(T) * 64,                          \
         (u16*)((LBASE) + 32768 + r1s * 128)); }

#define RD_AQ(QM, LB)                                                         \
  _Pragma("unroll") for (int mm = 0; mm < 4; ++mm) {                          \
    const int ro = (QM) * 8192 + mm * 2048;                                   \
    aF0[mm] = *(const bf16x8*)((LB) + aB0 + ro);                              \
    aF1[mm] = *(const bf16x8*)((LB) + aB1 + ro);                              \
  }

#define RD_BH(D0, D1, QN, LB)                                                 \
  _Pragma("unroll") for (int nn = 0; nn < 2; ++nn) {                          \
    const int co = (QN) * 4096 + nn * 2048;                                   \
    D0[nn] = *(const bf16x8*)((LB) + bB0 + co);                               \
    D1[nn] = *(const bf16x8*)((LB) + bB1 + co);                               \
  }

#define MMH(QM, QN, B0, B1)                                                   \
  __builtin_amdgcn_s_setprio(1);                                              \
  _Pragma("unroll") for (int mm = 0; mm < 4; ++mm)                            \
    _Pragma("unroll") for (int nn = 0; nn < 2; ++nn)                          \
      acc[(QM) * 4 + mm][(QN) * 2 + nn] =                                     \
          __builtin_amdgcn_mfma_f32_16x16x32_bf16(                            \
              aF0[mm], B0[nn], acc[(QM) * 4 + mm][(QN) * 2 + nn], 0, 0, 0);   \
  _Pragma("unroll") for (int mm = 0; mm < 4; ++mm)                            \
    _Pragma("unroll") for (int nn = 0; nn < 2; ++nn)                          \
      acc[(QM) * 4 + mm][(QN) * 2 + nn] =                                     \
          __builtin_amdgcn_mfma_f32_16x16x32_bf16(                            \
              aF1[mm], B1[nn], acc[(QM) * 4 + mm][(QN) * 2 + nn], 0, 0, 0);   \
  __builtin_amdgcn_s_setprio(0);

  // tile u (buffer LB) staging tile T=u+2 into LB; WAITSTMT at P4-end.
#define TILE(LB, T, WAITSTMT)                                                 \
  RD_AQ(0, LB) RD_BH(b0h0, b0h1, 0, LB)                                       \
  BAR LGK0 MMH(0, 0, b0h0, b0h1) BAR                                          \
  RD_BH(b1h0, b1h1, 1, LB)                                                    \
  STAGE_A(0, T, LB) STAGE_B(0, T, LB)                                         \
  BAR LGK0 MMH(0, 1, b1h0, b1h1) BAR                                          \
  RD_AQ(1, LB)                                                                \
  STAGE_B(1, T, LB)                                                           \
  BAR LGK0 MMH(1, 1, b1h0, b1h1) BAR                                          \
  STAGE_A(1, T, LB)                                                           \
  BAR MMH(1, 0, b0h0, b0h1) WAITSTMT BAR

  // ---- prologue: stage tiles 0 and 1 ----
  STAGE_A(0, 0, L0) STAGE_B(0, 0, L0) STAGE_B(1, 0, L0) STAGE_A(1, 0, L0)
  STAGE_A(0, 1, L1) STAGE_B(0, 1, L1) STAGE_B(1, 1, L1) STAGE_A(1, 1, L1)
  VMW(8)   // newest 8 = tile 1's loads -> tile 0 fully retired (this wave)
  BAR      // -> all waves

  // ---- main: tiles 0..13 stage tiles 2..15 ----
#pragma unroll 1
  for (int u0 = 0; u0 < 14; u0 += 2) {
    TILE(L0, u0 + 2, VMW(8))
    TILE(L1, u0 + 3, VMW(8))
  }

  // ---- tile 14 (L0, no staging; drain tile-15 loads at end) ----
  RD_AQ(0, L0) RD_BH(b0h0, b0h1, 0, L0)
  BAR LGK0 MMH(0, 0, b0h0, b0h1) BAR
  RD_BH(b1h0, b1h1, 1, L0)
  BAR LGK0 MMH(0, 1, b1h0, b1h1) BAR
  RD_AQ(1, L0)
  BAR LGK0 MMH(1, 1, b1h0, b1h1) BAR
  BAR MMH(1, 0, b0h0, b0h1) VMW(0) BAR
  // ---- tile 15 (L1) ----
  RD_AQ(0, L1) RD_BH(b0h0, b0h1, 0, L1)
  BAR LGK0 MMH(0, 0, b0h0, b0h1) BAR
  RD_BH(b1h0, b1h1, 1, L1)
  BAR LGK0 MMH(0, 1, b1h0, b1h1) BAR
  RD_AQ(1, L1)
  BAR LGK0 MMH(1, 1, b1h0, b1h1)
  MMH(1, 0, b0h0, b0h1)

#undef TILE
#undef MMH
#undef RD_BH
#undef RD_AQ
#undef STAGE_B
#undef STAGE_A
#undef BAR
#undef LGK0
#undef VMW

  const float* summ = g.summ;
#pragma unroll
  for (int m = 0; m < 8; ++m) {
    const size_t rbase = row0 + wm * 128 + m * 16 + q * 4;
#pragma unroll
    for (int n = 0; n < 4; ++n) {
      const size_t c = col0 + wn * 64 + n * 16 + cl;
      const float bb = bias[c];
#pragma unroll
      for (int e = 0; e < 4; ++e) {
        float v = acc[m][n][e] + bb;
        if (summ)
          v += summ[(size_t)((int)((rbase + e) >> 8) + g.srow0) * 1024 + c];
        if (g.Cf) g.Cf[(rbase + e) * 1024 + c] = v;
        else      C[(rbase + e) * 1024 + c] = f2b(v);
      }
    }
  }
}

// ---------------------------------------------------------------------------
// Local block attention. grid (4 qtiles, 16 heads, nblk), 256 threads.
// ---------------------------------------------------------------------------
__global__ __launch_bounds__(256, 2) void local_attn(
    const u16* __restrict__ Q, const u16* __restrict__ Kt,
    const u16* __restrict__ Vt, const float* __restrict__ pbias,
    u16* __restrict__ ctx) {
  const int qt  = blockIdx.x;
  const int h   = blockIdx.y;
  const int blk = blockIdx.z;
  const int tid  = threadIdx.x;
  const int lane = tid & 63;
  const int w    = tid >> 6;
  const int quad = lane >> 4;
  const int cl   = lane & 15;

  __shared__ u16 BufA[64 * 72];
  __shared__ u16 BufB[64 * 72];

  const size_t tok0  = (size_t)blk * 256;
  const size_t qrow0 = tok0 + qt * 64;
  const int hc = h * 64;

  for (int i = tid; i < 512; i += 256) {
    const int row = i >> 3, c8 = (i & 7) * 8;
    *(u16x8*)&BufA[row * 72 + c8] =
        *(const u16x8*)&Q[(qrow0 + row) * 1024 + hc + c8];
  }

  floatx4 accS[16] = {};
#pragma unroll
  for (int kc = 0; kc < 4; ++kc) {
    __syncthreads();
    for (int i = tid; i < 512; i += 256) {
      const int row = i >> 3, c8 = (i & 7) * 8;
      *(u16x8*)&BufB[row * 72 + c8] =
          *(const u16x8*)&Kt[(tok0 + kc * 64 + row) * 1024 + hc + c8];
    }
    __syncthreads();
#pragma unroll
    for (int ki = 0; ki < 2; ++ki) {
      const bf16x8 aq =
          *(const bf16x8*)&BufA[(w * 16 + cl) * 72 + ki * 32 + quad * 8];
#pragma unroll
      for (int n = 0; n < 4; ++n) {
        const bf16x8 bk =
            *(const bf16x8*)&BufB[(n * 16 + cl) * 72 + ki * 32 + quad * 8];
        accS[kc * 4 + n] = __builtin_amdgcn_mfma_f32_16x16x32_bf16(
            aq, bk, accS[kc * 4 + n], 0, 0, 0);
      }
    }
  }

  float mrow[4] = {-1e30f, -1e30f, -1e30f, -1e30f};
#pragma unroll
  for (int r = 0; r < 4; ++r) {
    const float* brow = pbias + ((size_t)h << 16) +
                        (size_t)(qt * 64 + w * 16 + quad * 4 + r) * 256 + cl;
#pragma unroll
    for (int n = 0; n < 16; ++n) {
      float s = accS[n][r] * 0.125f + brow[n * 16];
      accS[n][r] = s;
      mrow[r] = fmaxf(mrow[r], s);
    }
  }
#pragma unroll
  for (int r = 0; r < 4; ++r) {
#pragma unroll
    for (int st = 1; st < 16; st <<= 1)
      mrow[r] = fmaxf(mrow[r], __shfl_xor(mrow[r], st));
  }
  float lsum[4] = {0.f, 0.f, 0.f, 0.f};
#pragma unroll
  for (int n = 0; n < 16; ++n) {
#pragma unroll
    for (int r = 0; r < 4; ++r) {
      float p = exp2f((accS[n][r] - mrow[r]) * 1.44269504f);
      accS[n][r] = p;
      lsum[r] += p;
    }
  }
#pragma unroll
  for (int r = 0; r < 4; ++r) {
#pragma unroll
    for (int st = 1; st < 16; st <<= 1)
      lsum[r] += __shfl_xor(lsum[r], st);
  }

  floatx4 accO[4] = {};
#pragma unroll
  for (int kc = 0; kc < 4; ++kc) {
    __syncthreads();
#pragma unroll
    for (int nn = 0; nn < 4; ++nn)
#pragma unroll
      for (int r = 0; r < 4; ++r)
        BufA[(w * 16 + quad * 4 + r) * 72 + nn * 16 + cl] =
            f2b(accS[kc * 4 + nn][r]);
    for (int i = tid; i < 512; i += 256) {
      const int key = i & 63, dh0 = (i >> 6) * 8;
      u16x8 v = *(const u16x8*)&Vt[(tok0 + kc * 64 + key) * 1024 + hc + dh0];
#pragma unroll
      for (int j = 0; j < 8; ++j) BufB[(dh0 + j) * 72 + key] = v[j];
    }
    __syncthreads();
#pragma unroll
    for (int ki = 0; ki < 2; ++ki) {
      const bf16x8 ap =
          *(const bf16x8*)&BufA[(w * 16 + cl) * 72 + ki * 32 + quad * 8];
#pragma unroll
      for (int nd = 0; nd < 4; ++nd) {
        const bf16x8 bv =
            *(const bf16x8*)&BufB[(nd * 16 + cl) * 72 + ki * 32 + quad * 8];
        accO[nd] = __builtin_amdgcn_mfma_f32_16x16x32_bf16(ap, bv, accO[nd],
                                                           0, 0, 0);
      }
    }
  }

  float inv[4];
#pragma unroll
  for (int r = 0; r < 4; ++r) inv[r] = 1.0f / lsum[r];
#pragma unroll
  for (int nd = 0; nd < 4; ++nd)
#pragma unroll
    for (int r = 0; r < 4; ++r)
      ctx[(qrow0 + w * 16 + quad * 4 + r) * 1024 + hc + nd * 16 + cl] =
          f2b(accO[nd][r] * inv[r]);
}

// ---------------------------------------------------------------------------
// Conversions & summary-branch helpers
// ---------------------------------------------------------------------------
__global__ void cvt_x(const float* __restrict__ x, u16* __restrict__ xb) {
  const size_t i = ((size_t)blockIdx.x * 256 + threadIdx.x) * 4;
  float4 v = *(const float4*)&x[i];
  u16x4 o;
  o[0] = f2b(v.x); o[1] = f2b(v.y); o[2] = f2b(v.z); o[3] = f2b(v.w);
  *(u16x4*)&xb[i] = o;
}

__global__ void block_mean(const float* __restrict__ x, u16* __restrict__ xm) {
  const int g = blockIdx.x >> 2;
  const int d = ((blockIdx.x & 3) << 8) + threadIdx.x;
  const float* p = x + (size_t)g * 256 * 1024 + d;
  float s = 0.f;
  for (int t = 0; t < 256; ++t) s += p[(size_t)t * 1024];
  xm[(size_t)g * 1024 + d] = f2b(s * (1.0f / 256.0f));
}

__global__ void summ_attn(const u16* __restrict__ SQ, const u16* __restrict__ SK,
                          const u16* __restrict__ SV, u16* __restrict__ sctx) {
  const int b = blockIdx.x >> 4;
  const int h = blockIdx.x & 15;
  const int t = threadIdx.x;
  __shared__ float Qf[16][64];
  __shared__ float Kf[16][64];
  __shared__ float Vf[16][64];
  __shared__ float sc[16][16];
  for (int i = t; i < 1024; i += 64) {
    const int r = i >> 6, d = i & 63;
    const size_t off = (size_t)(b * 16 + r) * 1024 + h * 64 + d;
    Qf[r][d] = b2f(SQ[off]);
    Kf[r][d] = b2f(SK[off]);
    Vf[r][d] = b2f(SV[off]);
  }
  __syncthreads();
  {
    const int i = t >> 2, j0 = t & 3;
#pragma unroll
    for (int jj = 0; jj < 4; ++jj) {
      const int j = j0 + jj * 4;
      float s = 0.f;
      for (int d = 0; d < 64; ++d) s += Qf[i][d] * Kf[j][d];
      sc[i][j] = s * 0.125f;
    }
  }
  __syncthreads();
  if (t < 16) {
    float m = -1e30f;
    for (int j = 0; j < 16; ++j) m = fmaxf(m, sc[t][j]);
    float l = 0.f;
    for (int j = 0; j < 16; ++j) {
      float p = exp2f((sc[t][j] - m) * 1.44269504f);
      sc[t][j] = p;
      l += p;
    }
    const float inv = 1.0f / l;
    for (int j = 0; j < 16; ++j) sc[t][j] *= inv;
  }
  __syncthreads();
  {
    const int i = t >> 2, d0 = (t & 3) * 16;
    for (int dd = 0; dd < 16; ++dd) {
      float a = 0.f;
      for (int j = 0; j < 16; ++j) a += sc[i][j] * Vf[j][d0 + dd];
      sctx[(size_t)(b * 16 + i) * 1024 + h * 64 + d0 + dd] = f2b(a);
    }
  }
}

struct TPtrs { const float* src[9]; u16* dst[9]; };

__global__ void cvt_transpose9(TPtrs p) {
  const float* src = p.src[blockIdx.z];
  u16* dst         = p.dst[blockIdx.z];
  __shared__ u16 tile[64][72];
  const int r0 = blockIdx.x * 64, c0 = blockIdx.y * 64;
  for (int i = threadIdx.x; i < 1024; i += 256) {
    const int row = i >> 4, c4 = (i & 15) * 4;
    float4 v = *(const float4*)&src[(size_t)(r0 + row) * 1024 + c0 + c4];
    tile[row][c4 + 0] = f2b(v.x);
    tile[row][c4 + 1] = f2b(v.y);
    tile[row][c4 + 2] = f2b(v.z);
    tile[row][c4 + 3] = f2b(v.w);
  }
  __syncthreads();
  for (int i = threadIdx.x; i < 512; i += 256) {
    const int row = i >> 3, c8 = (i & 7) * 8;
    u16x8 v;
#pragma unroll
    for (int j = 0; j < 8; ++j) v[j] = tile[c8 + j][row];
    *(u16x8*)&dst[(size_t)(c0 + row) * 1024 + r0 + c8] = v;
  }
}

// ---------------------------------------------------------------------------
extern "C" void kernel_launch(void* const* d_in, const int* in_sizes, int n_in,
                              void* d_out, int out_size, void* d_ws, size_t ws_size,
                              hipStream_t stream) {
  const float* x    = (const float*)d_in[0];
  const float* lqw  = (const float*)d_in[1];
  const float* lqb  = (const float*)d_in[2];
  const float* lkw  = (const float*)d_in[3];
  const float* lkb  = (const float*)d_in[4];
  const float* lvw  = (const float*)d_in[5];
  const float* lvb  = (const float*)d_in[6];
  const float* low_ = (const float*)d_in[7];
  const float* lob  = (const float*)d_in[8];
  const float* pb   = (const float*)d_in[9];
  const float* sqw  = (const float*)d_in[10];
  const float* sqb  = (const float*)d_in[11];
  const float* skw  = (const float*)d_in[12];
  const float* skb  = (const float*)d_in[13];
  const float* svw  = (const float*)d_in[14];
  const float* svb  = (const float*)d_in[15];
  const float* sow  = (const float*)d_in[16];
  const float* sob  = (const float*)d_in[17];
  const float* smw  = (const float*)d_in[18];
  const float* smb  = (const float*)d_in[19];

  static int s_attr_done = 0;
  if (!s_attr_done) {
    (void)hipFuncSetAttribute((const void*)gemm_bt256,
                              hipFuncAttributeMaxDynamicSharedMemorySize,
                              131072);
    s_attr_done = 1;
  }

  char* W = (char*)d_ws;
  size_t off = 0;
  u16* wt[9];
  for (int i = 0; i < 9; ++i) { wt[i] = (u16*)(W + off); off += (size_t)1024 * 1024 * 2; }
  u16* Xb  = (u16*)(W + off); off += (size_t)16384 * 1024 * 2;
  u16* XM  = (u16*)(W + off); off += (size_t)128 * 1024 * 2;
  u16* SMR = (u16*)(W + off); off += (size_t)128 * 1024 * 2;
  u16* SQp = (u16*)(W + off); off += (size_t)128 * 1024 * 2;
  u16* SKp = (u16*)(W + off); off += (size_t)128 * 1024 * 2;
  u16* SVp = (u16*)(W + off); off += (size_t)128 * 1024 * 2;
  u16* SCT = (u16*)(W + off); off += (size_t)128 * 1024 * 2;
  float* SMM = (float*)(W + off); off += (size_t)128 * 1024 * 4;
  const size_t fixedB = off;

  int CH = 256;
  for (int c = 16384; c >= 256; c >>= 1) {
    if (fixedB + (size_t)4 * c * 1024 * 2 <= ws_size) { CH = c; break; }
  }
  u16* Qb  = (u16*)(W + fixedB);
  u16* Kb  = Qb + (size_t)CH * 1024;
  u16* Vb  = Kb + (size_t)CH * 1024;
  u16* CTX = Vb + (size_t)CH * 1024;

  TPtrs tp;
  tp.src[0] = lqw; tp.src[1] = lkw; tp.src[2] = lvw; tp.src[3] = low_;
  tp.src[4] = sqw; tp.src[5] = skw; tp.src[6] = svw; tp.src[7] = sow;
  tp.src[8] = smw;
  for (int i = 0; i < 9; ++i) tp.dst[i] = wt[i];
  cvt_transpose9<<<dim3(16, 16, 9), 256, 0, stream>>>(tp);

  cvt_x<<<dim3(16384), 256, 0, stream>>>(x, Xb);
  block_mean<<<dim3(256), 256, 0, stream>>>(x, XM);

  GemmArgs g1{};
  g1.A = XM; g1.BT0 = g1.BT1 = g1.BT2 = wt[8];
  g1.b0 = g1.b1 = g1.b2 = smb; g1.summ = nullptr; g1.srow0 = 0;
  g1.C0 = g1.C1 = g1.C2 = SMR; g1.Cf = nullptr;
  gemm_bt<<<dim3(1, 8, 1), 256, 0, stream>>>(g1);

  GemmArgs g2{};
  g2.A = SMR; g2.BT0 = wt[4]; g2.BT1 = wt[5]; g2.BT2 = wt[6];
  g2.b0 = sqb; g2.b1 = skb; g2.b2 = svb; g2.summ = nullptr; g2.srow0 = 0;
  g2.C0 = SQp; g2.C1 = SKp; g2.C2 = SVp; g2.Cf = nullptr;
  gemm_bt<<<dim3(1, 8, 3), 256, 0, stream>>>(g2);

  summ_attn<<<dim3(64), 64, 0, stream>>>(SQp, SKp, SVp, SCT);

  GemmArgs g3{};
  g3.A = SCT; g3.BT0 = g3.BT1 = g3.BT2 = wt[7];
  g3.b0 = g3.b1 = g3.b2 = sob; g3.summ = nullptr; g3.srow0 = 0;
  g3.C0 = g3.C1 = g3.C2 = nullptr; g3.Cf = SMM;
  gemm_bt<<<dim3(1, 8, 1), 256, 0, stream>>>(g3);

  for (int base = 0; base < 16384; base += CH) {
    GemmArgs g4{};
    g4.A = Xb + (size_t)base * 1024;
    g4.BT0 = wt[0]; g4.BT1 = wt[1]; g4.BT2 = wt[2];
    g4.b0 = lqb; g4.b1 = lkb; g4.b2 = lvb; g4.summ = nullptr; g4.srow0 = 0;
    g4.C0 = Qb; g4.C1 = Kb; g4.C2 = Vb; g4.Cf = nullptr;
    gemm_bt256<<<dim3(CH / 256, 4, 3), 512, 131072, stream>>>(g4);

    local_attn<<<dim3(4, 16, CH / 256), 256, 0, stream>>>(Qb, Kb, Vb, pb, CTX);

    GemmArgs g5{};
    g5.A = CTX; g5.BT0 = g5.BT1 = g5.BT2 = wt[3];
    g5.b0 = g5.b1 = g5.b2 = lob; g5.summ = SMM; g5.srow0 = base >> 8;
    g5.C0 = g5.C1 = g5.C2 = nullptr;
    g5.Cf = (float*)d_out + (size_t)base * 1024;
    gemm_bt256<<<dim3(CH / 256, 4, 1), 512, 131072, stream>>>(g5);
  }

  (void)in_sizes; (void)n_in; (void)out_size;
}